// Round 20
// baseline (725.849 us; speedup 1.0000x reference)
//
#include <hip/hip_runtime.h>

// Problem: B*T=3200 seqs, V=25, D=128, N_Q=4, N_E=1024. NROWS=80000.
// d_out: zq [10,240,000] | loss [1] | indices [320,000]
#define ZQ_N    10240000
#define IDX_OFF 10240001
#define FLT_BIG 3.402823466e38f

typedef _Float16 f16x8 __attribute__((ext_vector_type(8)));
typedef float    f32x4 __attribute__((ext_vector_type(4)));

// wsq[q*1024+j] = ||emb[q][j]||^2 (raw fp32 emb, scale-free); also zeroes loss_part.
__global__ __launch_bounds__(256) void k_wsq(const float* __restrict__ emb,
                                             float* __restrict__ wsq,
                                             float* __restrict__ loss_part) {
    int t = threadIdx.x;
    int g = blockIdx.x * 256 + t;
    if (g < 1024) loss_part[g] = 0.f;
    int row = blockIdx.x * 64 + (t >> 2);
    int seg = t & 3;
    const float4* p = (const float4*)(emb + row * 128 + seg * 32);
    float a = 0.f;
#pragma unroll
    for (int i = 0; i < 8; i++) {
        float4 w = p[i];
        a = fmaf(w.x, w.x, a); a = fmaf(w.y, w.y, a);
        a = fmaf(w.z, w.z, a); a = fmaf(w.w, w.w, a);
    }
    a += __shfl_xor(a, 1);
    a += __shfl_xor(a, 2);
    if (seg == 0) wsq[row] = a;
}

// split emb*1024 into f16x2 AND pre-pack into per-wave load order for the
// 8-wave/16-col-subpanel tile: col = w*128 + p*16 + lm (w 0..7, p 0..7),
// k = ks*32 + quad*8 + j.  packed off = ((w*8 + p)*4 + ks)*512 + (quad*16+lm)*8.
// Each k_vq B-load reads 64 lanes x 16B fully contiguous (1KB/instr).
// Also folds in the gw*1024 f16x2 split for the first 64 blocks.
__global__ __launch_bounds__(256) void k_wsplit(const float* __restrict__ emb,
        _Float16* __restrict__ wh, _Float16* __restrict__ wl,
        const float* __restrict__ gw,
        _Float16* __restrict__ gh, _Float16* __restrict__ gl) {
    int c = blockIdx.x * 256 + threadIdx.x;   // 65536 chunks of 8 elems
    int q   = c >> 14;                        // stage
    int col = (c >> 4) & 1023;
    int k8  = (c & 15) * 8;                   // k = k8 + j
    const float* srcp = emb + q * 131072 + col * 128 + k8;
    float4 a = *(const float4*)(srcp);
    float4 b = *(const float4*)(srcp + 4);
    float vv[8] = {a.x, a.y, a.z, a.w, b.x, b.y, b.z, b.w};
    union { _Float16 h[8]; uint4 u4; } ph, pl;
#pragma unroll
    for (int j = 0; j < 8; j++) {
        float v = vv[j] * 1024.f;             // exact pow2 scale
        _Float16 h = (_Float16)v;
        float r1 = v - (float)h;              // exact (Sterbenz)
        ph.h[j] = h; pl.h[j] = (_Float16)r1;
    }
    int w  = col >> 7, p = (col >> 4) & 7, lm = col & 15;
    int ks = k8 >> 5, quad = (k8 >> 3) & 3;
    int off = ((w * 8 + p) * 4 + ks) * 512 + (quad * 16 + lm) * 8;
    *(uint4*)(wh + q * 131072 + off) = ph.u4;
    *(uint4*)(wl + q * 131072 + off) = pl.u4;

    if (c < 16384) {                          // gw split ([d][k] native layout)
        float v = gw[c] * 1024.f;
        _Float16 h = (_Float16)v;
        float r1 = v - (float)h;
        gh[c] = h; gl[c] = (_Float16)r1;
    }
}

// One block per sequence: residual reconstruct (z - sum of previous codebook rows,
// same fp32 subtraction order as the old staged chain -> bitwise identical) +
// ring-GCN + MFMA linear (f16x2 split) + LeakyReLU + LN + res add.
// LDS: nei (fp32 MFMA output) aliases nh/nl (disjoint lifetimes).
__global__ __launch_bounds__(256) void k_refine(const float* __restrict__ zbase,
        const float* __restrict__ emb, const float* __restrict__ idx_f, int stage,
        float* __restrict__ refined, float* __restrict__ s_out,
        const float* __restrict__ An,
        const _Float16* __restrict__ gh, const _Float16* __restrict__ gl,
        const float* __restrict__ gb, const float* __restrict__ lsc,
        const float* __restrict__ lbi) {
    __shared__ __align__(16) float Rn[25 * 128];
    __shared__ __align__(16) unsigned char nbuf[2 * 32 * 136 * 2];  // nh | nl | (alias) nei
    __shared__ float Al[625];
    __shared__ int cds[75];                         // [25 rows][3 prev codes]
    _Float16* nh = (_Float16*)nbuf;                 // 32*136 f16
    _Float16* nl = (_Float16*)(nbuf + 8704);        // 32*136 f16
    float*    nei = (float*)nbuf;                   // 32*132 fp32 (16896B <= 17408B)
    const int tid = threadIdx.x;
    const int n = blockIdx.x;

    if (tid < 75) {
        int r = tid / 3, j = tid - r * 3;
        if (j < stage) cds[tid] = (int)idx_f[(n * 25 + r) * 4 + j];
    }
    for (int i = tid; i < 625; i += 256) Al[i] = An[i];
    __syncthreads();

    // residual reconstruct: Rn = z - q0 - q1 - ... (ascending, same order as staged chain)
    const float4* zp = (const float4*)(zbase + n * 3200);
    float4* Rn4 = (float4*)Rn;
    for (int i = tid; i < 800; i += 256) {
        float4 rv = zp[i];
        int r = i >> 5, c4 = (i & 31) * 4;
#pragma unroll
        for (int j = 0; j < 3; j++) {
            if (j < stage) {
                const float4 q = *(const float4*)(emb + j * 131072 + cds[r * 3 + j] * 128 + c4);
                rv.x -= q.x; rv.y -= q.y; rv.z -= q.z; rv.w -= q.w;
            }
        }
        Rn4[i] = rv;
    }
    __syncthreads();

    // ring-GCN fused with f16x2 split: nh+nl ~= 1024 * (A_norm @ Rn); rows 25-31 zero
    for (int i = tid; i < 512; i += 256) {      // 32 rows x 16 chunks of 8
        int r = i >> 4, k8 = (i & 15) * 8;
        union { _Float16 h[8]; uint4 u4; } ph, pl;
        if (r < 25) {
            int vm = (r == 0) ? 24 : r - 1;
            int vp = (r == 24) ? 0 : r + 1;
            float am = Al[r * 25 + vm], a0 = Al[r * 25 + r], ap = Al[r * 25 + vp];
#pragma unroll
            for (int j = 0; j < 8; j++) {
                int d = k8 + j;
                float val = am * Rn[vm * 128 + d];
                val = fmaf(a0, Rn[r  * 128 + d], val);
                val = fmaf(ap, Rn[vp * 128 + d], val);
                float v1 = val * 1024.f;          // exact pow2 scale
                _Float16 h = (_Float16)v1; float fh = (float)h;
                ph.h[j] = h; pl.h[j] = (_Float16)(v1 - fh);
            }
        } else {
            ph.u4 = make_uint4(0u, 0u, 0u, 0u);
            pl.u4 = make_uint4(0u, 0u, 0u, 0u);
        }
        int off = r * 136 + k8;
        *(uint4*)(&nh[off]) = ph.u4;
        *(uint4*)(&nl[off]) = pl.u4;
    }
    __syncthreads();

    // MFMA: out[25x128] = nei_gcn @ gw^T, per wave 32 cols (2 ct), 2 row tiles, K=128.
    {
        const int lane = tid & 63;
        const int wv   = tid >> 6;
        const int quad = lane >> 4;
        const int lm   = lane & 15;
        const int bbase = (wv * 32 + lm) * 128 + quad * 8;  // gw row = output col
        const int abase = lm * 136 + quad * 8;

        f32x4 racc[2][2];                                   // [ct][mt]
#pragma unroll
        for (int a = 0; a < 2; a++)
#pragma unroll
            for (int b = 0; b < 2; b++) racc[a][b] = (f32x4){0.f, 0.f, 0.f, 0.f};

#pragma unroll
        for (int k0 = 0; k0 < 4; k0++) {
            const int ko = k0 * 32;
            f16x8 ah[2], al[2];
#pragma unroll
            for (int mt = 0; mt < 2; mt++) {
                ah[mt] = *(const f16x8*)(&nh[abase + mt * (16 * 136) + ko]);
                al[mt] = *(const f16x8*)(&nl[abase + mt * (16 * 136) + ko]);
            }
            f16x8 bh[2], bl[2];
#pragma unroll
            for (int ct = 0; ct < 2; ct++) {
                bh[ct] = *(const f16x8*)(gh + bbase + ct * (16 * 128) + ko);
                bl[ct] = *(const f16x8*)(gl + bbase + ct * (16 * 128) + ko);
            }
            // pass-major: each racc[ct][mt] gets hh, hl, lh in order (bitwise same sum)
#pragma unroll
            for (int ct = 0; ct < 2; ct++)
#pragma unroll
                for (int mt = 0; mt < 2; mt++)
                    racc[ct][mt] = __builtin_amdgcn_mfma_f32_16x16x32_f16(ah[mt], bh[ct], racc[ct][mt], 0, 0, 0);
#pragma unroll
            for (int ct = 0; ct < 2; ct++)
#pragma unroll
                for (int mt = 0; mt < 2; mt++)
                    racc[ct][mt] = __builtin_amdgcn_mfma_f32_16x16x32_f16(ah[mt], bl[ct], racc[ct][mt], 0, 0, 0);
#pragma unroll
            for (int ct = 0; ct < 2; ct++)
#pragma unroll
                for (int mt = 0; mt < 2; mt++)
                    racc[ct][mt] = __builtin_amdgcn_mfma_f32_16x16x32_f16(al[mt], bh[ct], racc[ct][mt], 0, 0, 0);
        }

        // nh/nl are dead from here; barrier, then write nei into the SAME storage.
        __syncthreads();

        // C write: row = mt*16 + quad*4 + reg, col = wv*32 + ct*16 + lm
        // 9.5367431640625e-07 = 2^-20 (exact)
#pragma unroll
        for (int ct = 0; ct < 2; ct++)
#pragma unroll
            for (int mt = 0; mt < 2; mt++)
#pragma unroll
                for (int rg = 0; rg < 4; rg++) {
                    int row = mt * 16 + quad * 4 + rg;
                    if (row < 25)
                        nei[row * 132 + wv * 32 + ct * 16 + lm] =
                            racc[ct][mt][rg] * 9.5367431640625e-07f;
                }
    }
    __syncthreads();

    // epilogue: bias + LeakyReLU + LN + residual add (unchanged arithmetic)
    const int dpg = tid & 31;
    const int vs  = tid >> 5;
    const int dp0 = dpg * 4;

    float4 b4  = *(const float4*)(gb + dp0);
    float4 sc4 = *(const float4*)(lsc + dp0);
    float4 bi4 = *(const float4*)(lbi + dp0);
    const float bb[4] = {b4.x, b4.y, b4.z, b4.w};
    const float sc[4] = {sc4.x, sc4.y, sc4.z, sc4.w};
    const float bi[4] = {bi4.x, bi4.y, bi4.z, bi4.w};

#pragma unroll
    for (int i = 0; i < 4; i++) {
        int v = vs + 8 * i;
        if (v >= 25) break;
        float4 y4 = *(const float4*)(&nei[v * 132 + dp0]);
        const float yin[4] = {y4.x, y4.y, y4.z, y4.w};
        float y[4];
#pragma unroll
        for (int c = 0; c < 4; c++) {
            float t = yin[c] + bb[c];
            y[c] = (t >= 0.f) ? t : 0.2f * t;
        }
        float s1 = y[0] + y[1] + y[2] + y[3];
#pragma unroll
        for (int m = 1; m <= 16; m <<= 1) s1 += __shfl_xor(s1, m);
        float mu = s1 * (1.f / 128.f);
        float d2 = 0.f;
#pragma unroll
        for (int c = 0; c < 4; c++) { float t = y[c] - mu; d2 = fmaf(t, t, d2); }
#pragma unroll
        for (int m = 1; m <= 16; m <<= 1) d2 += __shfl_xor(d2, m);
        float inv = 1.f / sqrtf(d2 * (1.f / 128.f) + 1e-5f);

        float4 rn4 = *(const float4*)(&Rn[v * 128 + dp0]);
        const float rn[4] = {rn4.x, rn4.y, rn4.z, rn4.w};
        float o[4];
#pragma unroll
        for (int c = 0; c < 4; c++)
            o[c] = rn[c] + 0.1f * ((y[c] - mu) * inv * sc[c] + bi[c]);

        *(float4*)(refined + (n * 25 + v) * 128 + dp0) =
            make_float4(o[0], o[1], o[2], o[3]);

        float ss = 0.f;
#pragma unroll
        for (int c = 0; c < 4; c++) ss = fmaf(o[c], o[c], ss);
#pragma unroll
        for (int m = 1; m <= 16; m <<= 1) ss += __shfl_xor(ss, m);
        if (dpg == 0) s_out[n * 25 + v] = ss;
    }
}

// ---- k_vq: 8-wave blocks (512 threads, __launch_bounds__(512,1)); each wave
// owns 128 cols. NEW: ks-outer / panel-inner in 2 groups of 4 panels — each A
// k-band is read ONCE per group (2 full A-tile reads/wave vs 8) -> block LDS
// reads drop 2048 -> 512 b128 (R19 showed the kernel is LDS-pipe-bound, not
// latency-bound). acc[pi][rt] gets its ks-ascending hh/hl/lh contributions in
// the same order as before -> bitwise identical distances; cols ascend per
// lane (group-major, pi-minor) -> same tie-breaks. ----

#define XPAD 140

#define VQ_LOADA(KS) do {                                                      \
    _Pragma("unroll")                                                          \
    for (int _rt = 0; _rt < 4; _rt++) {                                        \
        const int _off = abase + _rt * (16 * XPAD) + (KS) * 32;                \
        ah[_rt] = *(const f16x8*)(&xh_s[_off]);                                \
        al[_rt] = *(const f16x8*)(&xl_s[_off]);                                \
    }                                                                          \
} while (0)

// packed: (w,p,ks) groups of 512 elems; lane*8 inside.
#define VQ_LOADB(BH, BL, P, KS) do {                                           \
    const int _o = ((w * 8 + (P)) * 4 + (KS)) * 512 + lane * 8;                \
    BH = *(const f16x8*)(wh + _o);                                             \
    BL = *(const f16x8*)(wl + _o);                                             \
} while (0)

// Pass-major (4 independent rt chains); per-acc order hh, hl, lh unchanged.
#define VQ_MMA(PI, BH, BL) do {                                                \
    _Pragma("unroll")                                                          \
    for (int _rt = 0; _rt < 4; _rt++)                                          \
        acc[PI][_rt] = __builtin_amdgcn_mfma_f32_16x16x32_f16(ah[_rt], BH, acc[PI][_rt], 0, 0, 0); \
    _Pragma("unroll")                                                          \
    for (int _rt = 0; _rt < 4; _rt++)                                          \
        acc[PI][_rt] = __builtin_amdgcn_mfma_f32_16x16x32_f16(ah[_rt], BL, acc[PI][_rt], 0, 0, 0); \
    _Pragma("unroll")                                                          \
    for (int _rt = 0; _rt < 4; _rt++)                                          \
        acc[PI][_rt] = __builtin_amdgcn_mfma_f32_16x16x32_f16(al[_rt], BH, acc[PI][_rt], 0, 0, 0); \
} while (0)

#define VQ_ZERO do {                                                           \
    _Pragma("unroll")                                                          \
    for (int _a = 0; _a < 4; _a++)                                             \
        _Pragma("unroll")                                                      \
        for (int _b = 0; _b < 4; _b++) acc[_a][_b] = (f32x4){0.f, 0.f, 0.f, 0.f}; \
} while (0)

// IT = ks*4 + pi (ks-outer, pi-inner). Prefetch next B; load A at pi==0.
// G==0, IT==15 prefetches group 1's first B (overlaps EPI(0)).
#define PIPE(G, IT, CH, CL, NH, NL) do {                                       \
    if ((IT) < 15) VQ_LOADB(NH, NL, (G) * 4 + (((IT) + 1) & 3), ((IT) + 1) >> 2); \
    else if ((G) == 0) VQ_LOADB(NH, NL, 4, 0);                                 \
    if (((IT) & 3) == 0) VQ_LOADA((IT) >> 2);                                  \
    VQ_MMA((IT) & 3, CH, CL);                                                  \
} while (0)

// dist = (||x||^2 - 2 x.w) + ||w||^2 ; running argmin; cols ascend -> strict <.
// 1.9073486328125e-06 = 2^-19 (exact): 2*(x.w) = acc * 2^-19.
#define VQ_EPI(G) do {                                                         \
    float _sr[16];                                                             \
    _Pragma("unroll")                                                          \
    for (int _rt = 0; _rt < 4; _rt++) {                                        \
        float4 _t = *(const float4*)(s_g + row0 + _rt * 16 + quad * 4);        \
        _sr[_rt * 4 + 0] = _t.x; _sr[_rt * 4 + 1] = _t.y;                      \
        _sr[_rt * 4 + 2] = _t.z; _sr[_rt * 4 + 3] = _t.w;                      \
    }                                                                          \
    _Pragma("unroll")                                                          \
    for (int _pi = 0; _pi < 4; _pi++) {                                        \
        const int _col = w * 128 + ((G) * 4 + _pi) * 16 + lm;                  \
        const float _wq = wsq_k[_col];                                         \
        _Pragma("unroll")                                                      \
        for (int _rt = 0; _rt < 4; _rt++) {                                    \
            _Pragma("unroll")                                                  \
            for (int _rg = 0; _rg < 4; _rg++) {                                \
                float _d = (_sr[_rt * 4 + _rg]                                 \
                            - 1.9073486328125e-06f * acc[_pi][_rt][_rg]) + _wq;\
                int _s = _rt * 4 + _rg;                                        \
                if (_d < bestv[_s]) { bestv[_s] = _d; besti[_s] = _col; }      \
            }                                                                  \
        }                                                                      \
    }                                                                          \
} while (0)

// MFMA distance GEMM via f16x2 split (scaled 2^10, denorm-proof) + exact argmin.
__global__ __launch_bounds__(512, 1) void k_vq(const float* __restrict__ refined,
        const _Float16* __restrict__ wh,   // [packed] f16 (x1024), this stage
        const _Float16* __restrict__ wl,
        const float* __restrict__ wsq_k,
        const float* __restrict__ s_g,
        float* __restrict__ idx_out, int stage) {
    __shared__ __align__(16) _Float16 xh_s[64 * XPAD];  // row stride 140 (bank-spread)
    __shared__ __align__(16) _Float16 xl_s[64 * XPAD];
    const int tid = threadIdx.x;
    const int row0 = blockIdx.x * 64;

    const int lane = tid & 63;
    const int w    = tid >> 6;       // wave id 0..7: cols w*128 + [0,128)
    const int quad = lane >> 4;
    const int lm   = lane & 15;

    const int abase = lm * XPAD + quad * 8;

    // issue first B load before staging: completes under staging + barrier
    f16x8 ah[4], al[4];
    f16x8 b0h, b0l, b1h, b1l;
    VQ_LOADB(b0h, b0l, 0, 0);

    // stage X tile: fp32*1024 -> f16x2 split into LDS
    for (int i = tid; i < 1024; i += 512) {       // 8-elem chunks
        int r = i >> 4, k8 = (i & 15) * 8;
        const float* srcp = refined + (row0 + r) * 128 + k8;
        float4 a = *(const float4*)(srcp);
        float4 b = *(const float4*)(srcp + 4);
        float vv[8] = {a.x, a.y, a.z, a.w, b.x, b.y, b.z, b.w};
        union { _Float16 h[8]; uint4 u4; } ph, pl;
#pragma unroll
        for (int j = 0; j < 8; j++) {
            float v = vv[j] * 1024.f;             // exact pow2 scale
            _Float16 h = (_Float16)v; float fh = (float)h;
            float r1 = v - fh;                    // exact (Sterbenz)
            ph.h[j] = h; pl.h[j] = (_Float16)r1;
        }
        int off = r * XPAD + k8;
        *(uint4*)(&xh_s[off]) = ph.u4;
        *(uint4*)(&xl_s[off]) = pl.u4;
    }
    __syncthreads();

    float bestv[16];
    int   besti[16];
#pragma unroll
    for (int s = 0; s < 16; s++) { bestv[s] = FLT_BIG; besti[s] = 0; }

    f32x4 acc[4][4];                              // [pi][rt]

    // ---- group 0: panels 0..3, ks-outer ----
    VQ_ZERO;
    PIPE(0, 0,  b0h, b0l, b1h, b1l);
    PIPE(0, 1,  b1h, b1l, b0h, b0l);
    PIPE(0, 2,  b0h, b0l, b1h, b1l);
    PIPE(0, 3,  b1h, b1l, b0h, b0l);
    PIPE(0, 4,  b0h, b0l, b1h, b1l);
    PIPE(0, 5,  b1h, b1l, b0h, b0l);
    PIPE(0, 6,  b0h, b0l, b1h, b1l);
    PIPE(0, 7,  b1h, b1l, b0h, b0l);
    PIPE(0, 8,  b0h, b0l, b1h, b1l);
    PIPE(0, 9,  b1h, b1l, b0h, b0l);
    PIPE(0, 10, b0h, b0l, b1h, b1l);
    PIPE(0, 11, b1h, b1l, b0h, b0l);
    PIPE(0, 12, b0h, b0l, b1h, b1l);
    PIPE(0, 13, b1h, b1l, b0h, b0l);
    PIPE(0, 14, b0h, b0l, b1h, b1l);
    PIPE(0, 15, b1h, b1l, b0h, b0l);   // prefetches (p=4, ks=0) into b0
    VQ_EPI(0);                          // overlaps group-1's first B load

    // ---- group 1: panels 4..7, ks-outer ----
    VQ_ZERO;
    PIPE(1, 0,  b0h, b0l, b1h, b1l);
    PIPE(1, 1,  b1h, b1l, b0h, b0l);
    PIPE(1, 2,  b0h, b0l, b1h, b1l);
    PIPE(1, 3,  b1h, b1l, b0h, b0l);
    PIPE(1, 4,  b0h, b0l, b1h, b1l);
    PIPE(1, 5,  b1h, b1l, b0h, b0l);
    PIPE(1, 6,  b0h, b0l, b1h, b1l);
    PIPE(1, 7,  b1h, b1l, b0h, b0l);
    PIPE(1, 8,  b0h, b0l, b1h, b1l);
    PIPE(1, 9,  b1h, b1l, b0h, b0l);
    PIPE(1, 10, b0h, b0l, b1h, b1l);
    PIPE(1, 11, b1h, b1l, b0h, b0l);
    PIPE(1, 12, b0h, b0l, b1h, b1l);
    PIPE(1, 13, b1h, b1l, b0h, b0l);
    PIPE(1, 14, b0h, b0l, b1h, b1l);
    PIPE(1, 15, b1h, b1l, b0h, b0l);
    VQ_EPI(1);

    // cross-lane argmin over lm (16 lanes hold same rows, different cols)
#pragma unroll
    for (int s = 0; s < 16; s++) {
#pragma unroll
        for (int m = 1; m <= 8; m <<= 1) {
            float ov = __shfl_xor(bestv[s], m);
            int   oi = __shfl_xor(besti[s], m);
            if (ov < bestv[s] || (ov == bestv[s] && oi < besti[s])) {
                bestv[s] = ov; besti[s] = oi;
            }
        }
    }

    __syncthreads();                 // done reading x LDS; alias reduction buffers
    float* redv = (float*)xh_s;      // [8][64]
    int*   redi = (int*)xl_s;        // [8][64]
    if (lm == 0) {
#pragma unroll
        for (int s = 0; s < 16; s++) {
            int row = (s >> 2) * 16 + quad * 4 + (s & 3);
            redv[w * 64 + row] = bestv[s];
            redi[w * 64 + row] = besti[s];
        }
    }
    __syncthreads();
    if (tid < 64) {
        float bv = redv[tid]; int bi = redi[tid];
#pragma unroll
        for (int ww = 1; ww < 8; ww++) {
            float v2 = redv[ww * 64 + tid]; int i2 = redi[ww * 64 + tid];
            if (v2 < bv || (v2 == bv && i2 < bi)) { bv = v2; bi = i2; }
        }
        idx_out[(row0 + tid) * 4 + stage] = (float)bi;
    }
}

// Replays the residual recurrence from z + indices: zq = sum q_k, loss_k = ||q_k - res_k||^2.
#define FIN_STAGE(K, ACC) do {                                                 \
    const float4 q = *(const float4*)(emb + (K) * 131072 + codes[r * 4 + (K)] * 128 + c4); \
    float dx = q.x - rv.x, dy = q.y - rv.y, dz = q.z - rv.z, dw = q.w - rv.w;  \
    ACC = fmaf(dx, dx, ACC); ACC = fmaf(dy, dy, ACC);                          \
    ACC = fmaf(dz, dz, ACC); ACC = fmaf(dw, dw, ACC);                          \
    s4.x += q.x; s4.y += q.y; s4.z += q.z; s4.w += q.w;                        \
    rv.x -= q.x; rv.y -= q.y; rv.z -= q.z; rv.w -= q.w;                        \
} while (0)

__global__ __launch_bounds__(256) void k_final(const float* __restrict__ z,
        const float* __restrict__ emb, const float* __restrict__ idx_f,
        float* __restrict__ zq, float* __restrict__ loss_part) {
    __shared__ int codes[256];       // [64 rows][4 stages]
    const int tid = threadIdx.x;
    const int row0 = blockIdx.x * 64;
    codes[tid] = (int)idx_f[row0 * 4 + tid];
    __syncthreads();

    const float4* zp = (const float4*)(z + row0 * 128);
    float4* zqp = (float4*)(zq + row0 * 128);
    float a0 = 0.f, a1 = 0.f, a2 = 0.f, a3 = 0.f;
#pragma unroll
    for (int j = 0; j < 8; j++) {
        int idx4 = tid + j * 256;
        int r = idx4 >> 5;
        int c4 = (idx4 & 31) * 4;
        float4 rv = zp[idx4];
        float4 s4 = make_float4(0.f, 0.f, 0.f, 0.f);
        FIN_STAGE(0, a0);
        FIN_STAGE(1, a1);
        FIN_STAGE(2, a2);
        FIN_STAGE(3, a3);
        zqp[idx4] = s4;
    }
#pragma unroll
    for (int m = 1; m <= 32; m <<= 1) {
        a0 += __shfl_xor(a0, m); a1 += __shfl_xor(a1, m);
        a2 += __shfl_xor(a2, m); a3 += __shfl_xor(a3, m);
    }
    if ((tid & 63) == 0) {
        float* slot = &loss_part[blockIdx.x & 1023];
        atomicAdd(slot, a0); atomicAdd(slot, a1);
        atomicAdd(slot, a2); atomicAdd(slot, a3);
    }
}

__global__ __launch_bounds__(256) void k_loss(const float* __restrict__ loss_part,
                                              float* __restrict__ out) {
    int t = threadIdx.x;
    float a = loss_part[t] + loss_part[t + 256] + loss_part[t + 512] + loss_part[t + 768];
#pragma unroll
    for (int m = 1; m <= 32; m <<= 1) a += __shfl_xor(a, m);
    __shared__ float w[4];
    if ((t & 63) == 0) w[t >> 6] = a;
    __syncthreads();
    if (t == 0) {
        float s = w[0] + w[1] + w[2] + w[3];
        out[ZQ_N] = s * (1.25f / (128.f * 320000.f));
    }
}

extern "C" void kernel_launch(void* const* d_in, const int* in_sizes, int n_in,
                              void* d_out, int out_size, void* d_ws, size_t ws_size,
                              hipStream_t stream) {
    (void)in_sizes; (void)n_in; (void)out_size; (void)ws_size;
    const float* z   = (const float*)d_in[0];
    const float* emb = (const float*)d_in[1];
    const float* An  = (const float*)d_in[2];
    const float* gw  = (const float*)d_in[3];
    const float* gb  = (const float*)d_in[4];
    const float* lsc = (const float*)d_in[5];
    const float* lbi = (const float*)d_in[6];

    float* out     = (float*)d_out;
    float* zq      = out;
    float* idx_out = out + IDX_OFF;

    float* ws        = (float*)d_ws;
    float* refined   = ws + 10240000;        // 10,240,000 (slot 0 unused)
    _Float16* gh_f16 = (_Float16*)(ws + 20480000);  // 16,384 halves (8,192 f)
    _Float16* gl_f16 = (_Float16*)(ws + 20488192);  // 16,384 halves
    _Float16* wh_f16 = (_Float16*)(ws + 20496384);  // 524,288 halves (262,144 f)
    _Float16* wl_f16 = (_Float16*)(ws + 20758528);  // 524,288 halves
    float* s_g       = ws + 21020672;        // 80,000
    float* wsq       = ws + 21100672;        // 4,096
    float* loss_part = ws + 21104768;        // 1,024  (end: 21,105,792 floats)

    k_wsq<<<64, 256, 0, stream>>>(emb, wsq, loss_part);
    k_wsplit<<<256, 256, 0, stream>>>(emb, wh_f16, wl_f16, gw, gh_f16, gl_f16);
    for (int k = 0; k < 4; k++) {
        k_refine<<<3200, 256, 0, stream>>>(z, emb, idx_out, k,
                                           refined, s_g, An,
                                           gh_f16, gl_f16, gb, lsc, lbi);
        k_vq<<<1250, 512, 0, stream>>>(refined,
                                       wh_f16 + k * 131072, wl_f16 + k * 131072,
                                       wsq + k * 1024,
                                       s_g, idx_out, k);
    }
    k_final<<<1250, 256, 0, stream>>>(z, emb, idx_out, zq, loss_part);
    k_loss<<<1, 256, 0, stream>>>(loss_part, out);
}

// Round 21
// 698.721 us; speedup vs baseline: 1.0388x; 1.0388x over previous
//
#include <hip/hip_runtime.h>

// Problem: B*T=3200 seqs, V=25, D=128, N_Q=4, N_E=1024. NROWS=80000.
// d_out: zq [10,240,000] | loss [1] | indices [320,000]
#define ZQ_N    10240000
#define IDX_OFF 10240001
#define FLT_BIG 3.402823466e38f

typedef _Float16 f16x8 __attribute__((ext_vector_type(8)));
typedef float    f32x4 __attribute__((ext_vector_type(4)));

// wsq[q*1024+j] = ||emb[q][j]||^2 (raw fp32 emb, scale-free); also zeroes loss_part.
__global__ __launch_bounds__(256) void k_wsq(const float* __restrict__ emb,
                                             float* __restrict__ wsq,
                                             float* __restrict__ loss_part) {
    int t = threadIdx.x;
    int g = blockIdx.x * 256 + t;
    if (g < 1024) loss_part[g] = 0.f;
    int row = blockIdx.x * 64 + (t >> 2);
    int seg = t & 3;
    const float4* p = (const float4*)(emb + row * 128 + seg * 32);
    float a = 0.f;
#pragma unroll
    for (int i = 0; i < 8; i++) {
        float4 w = p[i];
        a = fmaf(w.x, w.x, a); a = fmaf(w.y, w.y, a);
        a = fmaf(w.z, w.z, a); a = fmaf(w.w, w.w, a);
    }
    a += __shfl_xor(a, 1);
    a += __shfl_xor(a, 2);
    if (seg == 0) wsq[row] = a;
}

// split emb*1024 into f16x2 AND pre-pack into per-wave load order for the
// 32-col-per-wave tile: col = P*128 + w*32 + ct*16 + lm (P 0..7, w 0..3, ct 0..1),
// k = ks*32 + quad*8 + j.  packed off = (((P*4+w)*4+ks)*2+ct)*512 + (quad*16+lm)*8.
// Each k_vq B-load reads 64 lanes x 16B fully contiguous (1KB/instr).
// Also folds in the gw*1024 f16x2 split for the first 64 blocks.
__global__ __launch_bounds__(256) void k_wsplit(const float* __restrict__ emb,
        _Float16* __restrict__ wh, _Float16* __restrict__ wl,
        const float* __restrict__ gw,
        _Float16* __restrict__ gh, _Float16* __restrict__ gl) {
    int c = blockIdx.x * 256 + threadIdx.x;   // 65536 chunks of 8 elems
    int q   = c >> 14;                        // stage
    int col = (c >> 4) & 1023;
    int k8  = (c & 15) * 8;                   // k = k8 + j
    const float* srcp = emb + q * 131072 + col * 128 + k8;
    float4 a = *(const float4*)(srcp);
    float4 b = *(const float4*)(srcp + 4);
    float vv[8] = {a.x, a.y, a.z, a.w, b.x, b.y, b.z, b.w};
    union { _Float16 h[8]; uint4 u4; } ph, pl;
#pragma unroll
    for (int j = 0; j < 8; j++) {
        float v = vv[j] * 1024.f;             // exact pow2 scale
        _Float16 h = (_Float16)v;
        float r1 = v - (float)h;              // exact (Sterbenz)
        ph.h[j] = h; pl.h[j] = (_Float16)r1;
    }
    int P  = col >> 7, w = (col >> 5) & 3, ct = (col >> 4) & 1, lm = col & 15;
    int ks = k8 >> 5, quad = (k8 >> 3) & 3;
    int off = (((P * 4 + w) * 4 + ks) * 2 + ct) * 512 + (quad * 16 + lm) * 8;
    *(uint4*)(wh + q * 131072 + off) = ph.u4;
    *(uint4*)(wl + q * 131072 + off) = pl.u4;

    if (c < 16384) {                          // gw split ([d][k] native layout)
        float v = gw[c] * 1024.f;
        _Float16 h = (_Float16)v;
        float r1 = v - (float)h;
        gh[c] = h; gl[c] = (_Float16)r1;
    }
}

// One block per sequence: residual reconstruct (z - sum of previous codebook rows,
// same fp32 subtraction order as the old staged chain -> bitwise identical) +
// ring-GCN + MFMA linear (f16x2 split) + LeakyReLU + LN + res add.
// LDS: nei (fp32 MFMA output) aliases nh/nl (disjoint lifetimes).
__global__ __launch_bounds__(256) void k_refine(const float* __restrict__ zbase,
        const float* __restrict__ emb, const float* __restrict__ idx_f, int stage,
        float* __restrict__ refined, float* __restrict__ s_out,
        const float* __restrict__ An,
        const _Float16* __restrict__ gh, const _Float16* __restrict__ gl,
        const float* __restrict__ gb, const float* __restrict__ lsc,
        const float* __restrict__ lbi) {
    __shared__ __align__(16) float Rn[25 * 128];
    __shared__ __align__(16) unsigned char nbuf[2 * 32 * 136 * 2];  // nh | nl | (alias) nei
    __shared__ float Al[625];
    __shared__ int cds[75];                         // [25 rows][3 prev codes]
    _Float16* nh = (_Float16*)nbuf;                 // 32*136 f16
    _Float16* nl = (_Float16*)(nbuf + 8704);        // 32*136 f16
    float*    nei = (float*)nbuf;                   // 32*132 fp32 (16896B <= 17408B)
    const int tid = threadIdx.x;
    const int n = blockIdx.x;

    if (tid < 75) {
        int r = tid / 3, j = tid - r * 3;
        if (j < stage) cds[tid] = (int)idx_f[(n * 25 + r) * 4 + j];
    }
    for (int i = tid; i < 625; i += 256) Al[i] = An[i];
    __syncthreads();

    // residual reconstruct: Rn = z - q0 - q1 - ... (ascending, same order as staged chain)
    const float4* zp = (const float4*)(zbase + n * 3200);
    float4* Rn4 = (float4*)Rn;
    for (int i = tid; i < 800; i += 256) {
        float4 rv = zp[i];
        int r = i >> 5, c4 = (i & 31) * 4;
#pragma unroll
        for (int j = 0; j < 3; j++) {
            if (j < stage) {
                const float4 q = *(const float4*)(emb + j * 131072 + cds[r * 3 + j] * 128 + c4);
                rv.x -= q.x; rv.y -= q.y; rv.z -= q.z; rv.w -= q.w;
            }
        }
        Rn4[i] = rv;
    }
    __syncthreads();

    // ring-GCN fused with f16x2 split: nh+nl ~= 1024 * (A_norm @ Rn); rows 25-31 zero
    for (int i = tid; i < 512; i += 256) {      // 32 rows x 16 chunks of 8
        int r = i >> 4, k8 = (i & 15) * 8;
        union { _Float16 h[8]; uint4 u4; } ph, pl;
        if (r < 25) {
            int vm = (r == 0) ? 24 : r - 1;
            int vp = (r == 24) ? 0 : r + 1;
            float am = Al[r * 25 + vm], a0 = Al[r * 25 + r], ap = Al[r * 25 + vp];
#pragma unroll
            for (int j = 0; j < 8; j++) {
                int d = k8 + j;
                float val = am * Rn[vm * 128 + d];
                val = fmaf(a0, Rn[r  * 128 + d], val);
                val = fmaf(ap, Rn[vp * 128 + d], val);
                float v1 = val * 1024.f;          // exact pow2 scale
                _Float16 h = (_Float16)v1; float fh = (float)h;
                ph.h[j] = h; pl.h[j] = (_Float16)(v1 - fh);
            }
        } else {
            ph.u4 = make_uint4(0u, 0u, 0u, 0u);
            pl.u4 = make_uint4(0u, 0u, 0u, 0u);
        }
        int off = r * 136 + k8;
        *(uint4*)(&nh[off]) = ph.u4;
        *(uint4*)(&nl[off]) = pl.u4;
    }
    __syncthreads();

    // MFMA: out[25x128] = nei_gcn @ gw^T, per wave 32 cols (2 ct), 2 row tiles, K=128.
    {
        const int lane = tid & 63;
        const int wv   = tid >> 6;
        const int quad = lane >> 4;
        const int lm   = lane & 15;
        const int bbase = (wv * 32 + lm) * 128 + quad * 8;  // gw row = output col
        const int abase = lm * 136 + quad * 8;

        f32x4 racc[2][2];                                   // [ct][mt]
#pragma unroll
        for (int a = 0; a < 2; a++)
#pragma unroll
            for (int b = 0; b < 2; b++) racc[a][b] = (f32x4){0.f, 0.f, 0.f, 0.f};

#pragma unroll
        for (int k0 = 0; k0 < 4; k0++) {
            const int ko = k0 * 32;
            f16x8 ah[2], al[2];
#pragma unroll
            for (int mt = 0; mt < 2; mt++) {
                ah[mt] = *(const f16x8*)(&nh[abase + mt * (16 * 136) + ko]);
                al[mt] = *(const f16x8*)(&nl[abase + mt * (16 * 136) + ko]);
            }
            f16x8 bh[2], bl[2];
#pragma unroll
            for (int ct = 0; ct < 2; ct++) {
                bh[ct] = *(const f16x8*)(gh + bbase + ct * (16 * 128) + ko);
                bl[ct] = *(const f16x8*)(gl + bbase + ct * (16 * 128) + ko);
            }
            // pass-major: each racc[ct][mt] gets hh, hl, lh in order (bitwise same sum)
#pragma unroll
            for (int ct = 0; ct < 2; ct++)
#pragma unroll
                for (int mt = 0; mt < 2; mt++)
                    racc[ct][mt] = __builtin_amdgcn_mfma_f32_16x16x32_f16(ah[mt], bh[ct], racc[ct][mt], 0, 0, 0);
#pragma unroll
            for (int ct = 0; ct < 2; ct++)
#pragma unroll
                for (int mt = 0; mt < 2; mt++)
                    racc[ct][mt] = __builtin_amdgcn_mfma_f32_16x16x32_f16(ah[mt], bl[ct], racc[ct][mt], 0, 0, 0);
#pragma unroll
            for (int ct = 0; ct < 2; ct++)
#pragma unroll
                for (int mt = 0; mt < 2; mt++)
                    racc[ct][mt] = __builtin_amdgcn_mfma_f32_16x16x32_f16(al[mt], bh[ct], racc[ct][mt], 0, 0, 0);
        }

        // nh/nl are dead from here; barrier, then write nei into the SAME storage.
        __syncthreads();

        // C write: row = mt*16 + quad*4 + reg, col = wv*32 + ct*16 + lm
        // 9.5367431640625e-07 = 2^-20 (exact)
#pragma unroll
        for (int ct = 0; ct < 2; ct++)
#pragma unroll
            for (int mt = 0; mt < 2; mt++)
#pragma unroll
                for (int rg = 0; rg < 4; rg++) {
                    int row = mt * 16 + quad * 4 + rg;
                    if (row < 25)
                        nei[row * 132 + wv * 32 + ct * 16 + lm] =
                            racc[ct][mt][rg] * 9.5367431640625e-07f;
                }
    }
    __syncthreads();

    // epilogue: bias + LeakyReLU + LN + residual add (unchanged arithmetic)
    const int dpg = tid & 31;
    const int vs  = tid >> 5;
    const int dp0 = dpg * 4;

    float4 b4  = *(const float4*)(gb + dp0);
    float4 sc4 = *(const float4*)(lsc + dp0);
    float4 bi4 = *(const float4*)(lbi + dp0);
    const float bb[4] = {b4.x, b4.y, b4.z, b4.w};
    const float sc[4] = {sc4.x, sc4.y, sc4.z, sc4.w};
    const float bi[4] = {bi4.x, bi4.y, bi4.z, bi4.w};

#pragma unroll
    for (int i = 0; i < 4; i++) {
        int v = vs + 8 * i;
        if (v >= 25) break;
        float4 y4 = *(const float4*)(&nei[v * 132 + dp0]);
        const float yin[4] = {y4.x, y4.y, y4.z, y4.w};
        float y[4];
#pragma unroll
        for (int c = 0; c < 4; c++) {
            float t = yin[c] + bb[c];
            y[c] = (t >= 0.f) ? t : 0.2f * t;
        }
        float s1 = y[0] + y[1] + y[2] + y[3];
#pragma unroll
        for (int m = 1; m <= 16; m <<= 1) s1 += __shfl_xor(s1, m);
        float mu = s1 * (1.f / 128.f);
        float d2 = 0.f;
#pragma unroll
        for (int c = 0; c < 4; c++) { float t = y[c] - mu; d2 = fmaf(t, t, d2); }
#pragma unroll
        for (int m = 1; m <= 16; m <<= 1) d2 += __shfl_xor(d2, m);
        float inv = 1.f / sqrtf(d2 * (1.f / 128.f) + 1e-5f);

        float4 rn4 = *(const float4*)(&Rn[v * 128 + dp0]);
        const float rn[4] = {rn4.x, rn4.y, rn4.z, rn4.w};
        float o[4];
#pragma unroll
        for (int c = 0; c < 4; c++)
            o[c] = rn[c] + 0.1f * ((y[c] - mu) * inv * sc[c] + bi[c]);

        *(float4*)(refined + (n * 25 + v) * 128 + dp0) =
            make_float4(o[0], o[1], o[2], o[3]);

        float ss = 0.f;
#pragma unroll
        for (int c = 0; c < 4; c++) ss = fmaf(o[c], o[c], ss);
#pragma unroll
        for (int m = 1; m <= 16; m <<= 1) ss += __shfl_xor(ss, m);
        if (dpg == 0) s_out[n * 25 + v] = ss;
    }
}

// ---- k_vq: pure argmin producer; 32-col-per-wave tile; depth-1 double-buffer;
// packed B loads (64 lanes x 16B contiguous). Best-measured config (R14, 703us). ----

// packed: (P,w,ks) groups of 1024 elems; ct blocks of 512; lane*8 inside.
#define VQ_LOADB(BH, BL, IT) do {                                              \
    const int _o = ((((IT) >> 2) * 4 + w) * 4 + ((IT) & 3)) * 1024 + lane * 8; \
    BH[0] = *(const f16x8*)(wh + _o);        BL[0] = *(const f16x8*)(wl + _o);        \
    BH[1] = *(const f16x8*)(wh + _o + 512);  BL[1] = *(const f16x8*)(wl + _o + 512);  \
} while (0)

// Pass-major MFMA order; per-acc contribution order (hh, hl, lh) unchanged.
#define VQ_STEP(IT, BH, BL) do {                                               \
    const int _ko = abase + ((IT) & 3) * 32;                                   \
    f16x8 _ah[4], _al[4];                                                      \
    _Pragma("unroll")                                                          \
    for (int _rt = 0; _rt < 4; _rt++) {                                        \
        const int _off = _ko + _rt * (16 * 136);                               \
        _ah[_rt] = *(const f16x8*)(&xh_s[_off]);                               \
        _al[_rt] = *(const f16x8*)(&xl_s[_off]);                               \
    }                                                                          \
    _Pragma("unroll")                                                          \
    for (int _ct = 0; _ct < 2; _ct++)                                          \
        _Pragma("unroll")                                                      \
        for (int _rt = 0; _rt < 4; _rt++)                                      \
            acc[_ct][_rt] = __builtin_amdgcn_mfma_f32_16x16x32_f16(_ah[_rt], BH[_ct], acc[_ct][_rt], 0, 0, 0); \
    _Pragma("unroll")                                                          \
    for (int _ct = 0; _ct < 2; _ct++)                                          \
        _Pragma("unroll")                                                      \
        for (int _rt = 0; _rt < 4; _rt++)                                      \
            acc[_ct][_rt] = __builtin_amdgcn_mfma_f32_16x16x32_f16(_ah[_rt], BL[_ct], acc[_ct][_rt], 0, 0, 0); \
    _Pragma("unroll")                                                          \
    for (int _ct = 0; _ct < 2; _ct++)                                          \
        _Pragma("unroll")                                                      \
        for (int _rt = 0; _rt < 4; _rt++)                                      \
            acc[_ct][_rt] = __builtin_amdgcn_mfma_f32_16x16x32_f16(_al[_rt], BH[_ct], acc[_ct][_rt], 0, 0, 0); \
} while (0)

// dist = (||x||^2 - 2 x.w) + ||w||^2 ; running argmin.
// Per-lane cols ascend (P-major, then ct) -> strict < keeps lowest col.
// 1.9073486328125e-06 = 2^-19 (exact): 2*(x.w) = acc * 2^-19.
#define VQ_EPI(P) do {                                                         \
    float _sr[16];                                                             \
    _Pragma("unroll")                                                          \
    for (int _rt = 0; _rt < 4; _rt++) {                                        \
        float4 _t = *(const float4*)(s_g + row0 + _rt * 16 + quad * 4);        \
        _sr[_rt * 4 + 0] = _t.x; _sr[_rt * 4 + 1] = _t.y;                      \
        _sr[_rt * 4 + 2] = _t.z; _sr[_rt * 4 + 3] = _t.w;                      \
    }                                                                          \
    _Pragma("unroll")                                                          \
    for (int _ct = 0; _ct < 2; _ct++) {                                        \
        const int _col = (P) * 128 + w * 32 + _ct * 16 + lm;                   \
        const float _wq = wsq_k[_col];                                         \
        _Pragma("unroll")                                                      \
        for (int _rt = 0; _rt < 4; _rt++) {                                    \
            _Pragma("unroll")                                                  \
            for (int _rg = 0; _rg < 4; _rg++) {                                \
                float _d = (_sr[_rt * 4 + _rg]                                 \
                            - 1.9073486328125e-06f * acc[_ct][_rt][_rg]) + _wq;\
                int _s = _rt * 4 + _rg;                                        \
                if (_d < bestv[_s]) { bestv[_s] = _d; besti[_s] = _col; }      \
            }                                                                  \
        }                                                                      \
    }                                                                          \
} while (0)

// MFMA distance GEMM via f16x2 split (scaled 2^10, denorm-proof) + exact argmin.
__global__ __launch_bounds__(256) void k_vq(const float* __restrict__ refined,
        const _Float16* __restrict__ wh,   // [packed] f16 (x1024), this stage
        const _Float16* __restrict__ wl,
        const float* __restrict__ wsq_k,
        const float* __restrict__ s_g,
        float* __restrict__ idx_out, int stage) {
    __shared__ __align__(16) _Float16 xh_s[64 * 136];  // row stride 136 (pad 8)
    __shared__ __align__(16) _Float16 xl_s[64 * 136];
    const int tid = threadIdx.x;
    const int row0 = blockIdx.x * 64;

    const int lane = tid & 63;
    const int w    = tid >> 6;       // wave id: cols w*32 within each 128-panel
    const int quad = lane >> 4;
    const int lm   = lane & 15;

    const int abase = lm * 136 + quad * 8;

    // issue step-0 B loads first: they complete under X staging + barrier
    f16x8 bha[2], bla[2], bhb[2], blb[2];
    VQ_LOADB(bha, bla, 0);

    // stage X tile: fp32*1024 -> f16x2 split into LDS
    for (int i = tid; i < 1024; i += 256) {       // 8-elem chunks
        int r = i >> 4, k8 = (i & 15) * 8;
        const float* srcp = refined + (row0 + r) * 128 + k8;
        float4 a = *(const float4*)(srcp);
        float4 b = *(const float4*)(srcp + 4);
        float vv[8] = {a.x, a.y, a.z, a.w, b.x, b.y, b.z, b.w};
        union { _Float16 h[8]; uint4 u4; } ph, pl;
#pragma unroll
        for (int j = 0; j < 8; j++) {
            float v = vv[j] * 1024.f;             // exact pow2 scale
            _Float16 h = (_Float16)v; float fh = (float)h;
            float r1 = v - fh;                    // exact (Sterbenz)
            ph.h[j] = h; pl.h[j] = (_Float16)r1;
        }
        int off = r * 136 + k8;
        *(uint4*)(&xh_s[off]) = ph.u4;
        *(uint4*)(&xl_s[off]) = pl.u4;
    }
    __syncthreads();

    float bestv[16];
    int   besti[16];
#pragma unroll
    for (int s = 0; s < 16; s++) { bestv[s] = FLT_BIG; besti[s] = 0; }

    f32x4 acc[2][4];                              // [ct][rt]

#pragma unroll
    for (int ith = 0; ith < 16; ith++) {
        const int it0 = ith * 2, it1 = it0 + 1;
        // prefetch B for the odd step while the even step computes
        VQ_LOADB(bhb, blb, it1);
        if ((it0 & 3) == 0) {
#pragma unroll
            for (int a = 0; a < 2; a++)
#pragma unroll
                for (int b = 0; b < 4; b++) acc[a][b] = (f32x4){0.f, 0.f, 0.f, 0.f};
        }
        VQ_STEP(it0, bha, bla);
        // prefetch B for the next even step while the odd step computes
        if (it1 < 31) VQ_LOADB(bha, bla, it1 + 1);
        VQ_STEP(it1, bhb, blb);
        if ((it1 & 3) == 3) VQ_EPI(it1 >> 2);
    }

    // cross-lane argmin over lm (16 lanes hold same rows, different cols)
#pragma unroll
    for (int s = 0; s < 16; s++) {
#pragma unroll
        for (int m = 1; m <= 8; m <<= 1) {
            float ov = __shfl_xor(bestv[s], m);
            int   oi = __shfl_xor(besti[s], m);
            if (ov < bestv[s] || (ov == bestv[s] && oi < besti[s])) {
                bestv[s] = ov; besti[s] = oi;
            }
        }
    }

    __syncthreads();                 // done reading x LDS; alias reduction buffers
    float* redv = (float*)xh_s;      // [4][64]
    int*   redi = (int*)xl_s;        // [4][64]
    if (lm == 0) {
#pragma unroll
        for (int s = 0; s < 16; s++) {
            int row = (s >> 2) * 16 + quad * 4 + (s & 3);
            redv[w * 64 + row] = bestv[s];
            redi[w * 64 + row] = besti[s];
        }
    }
    __syncthreads();
    if (tid < 64) {
        float bv = redv[tid]; int bi = redi[tid];
#pragma unroll
        for (int ww = 1; ww < 4; ww++) {
            float v2 = redv[ww * 64 + tid]; int i2 = redi[ww * 64 + tid];
            if (v2 < bv || (v2 == bv && i2 < bi)) { bv = v2; bi = i2; }
        }
        idx_out[(row0 + tid) * 4 + stage] = (float)bi;
    }
}

// Replays the residual recurrence from z + indices: zq = sum q_k, loss_k = ||q_k - res_k||^2.
#define FIN_STAGE(K, ACC) do {                                                 \
    const float4 q = *(const float4*)(emb + (K) * 131072 + codes[r * 4 + (K)] * 128 + c4); \
    float dx = q.x - rv.x, dy = q.y - rv.y, dz = q.z - rv.z, dw = q.w - rv.w;  \
    ACC = fmaf(dx, dx, ACC); ACC = fmaf(dy, dy, ACC);                          \
    ACC = fmaf(dz, dz, ACC); ACC = fmaf(dw, dw, ACC);                          \
    s4.x += q.x; s4.y += q.y; s4.z += q.z; s4.w += q.w;                        \
    rv.x -= q.x; rv.y -= q.y; rv.z -= q.z; rv.w -= q.w;                        \
} while (0)

__global__ __launch_bounds__(256) void k_final(const float* __restrict__ z,
        const float* __restrict__ emb, const float* __restrict__ idx_f,
        float* __restrict__ zq, float* __restrict__ loss_part) {
    __shared__ int codes[256];       // [64 rows][4 stages]
    const int tid = threadIdx.x;
    const int row0 = blockIdx.x * 64;
    codes[tid] = (int)idx_f[row0 * 4 + tid];
    __syncthreads();

    const float4* zp = (const float4*)(z + row0 * 128);
    float4* zqp = (float4*)(zq + row0 * 128);
    float a0 = 0.f, a1 = 0.f, a2 = 0.f, a3 = 0.f;
#pragma unroll
    for (int j = 0; j < 8; j++) {
        int idx4 = tid + j * 256;
        int r = idx4 >> 5;
        int c4 = (idx4 & 31) * 4;
        float4 rv = zp[idx4];
        float4 s4 = make_float4(0.f, 0.f, 0.f, 0.f);
        FIN_STAGE(0, a0);
        FIN_STAGE(1, a1);
        FIN_STAGE(2, a2);
        FIN_STAGE(3, a3);
        zqp[idx4] = s4;
    }
#pragma unroll
    for (int m = 1; m <= 32; m <<= 1) {
        a0 += __shfl_xor(a0, m); a1 += __shfl_xor(a1, m);
        a2 += __shfl_xor(a2, m); a3 += __shfl_xor(a3, m);
    }
    if ((tid & 63) == 0) {
        float* slot = &loss_part[blockIdx.x & 1023];
        atomicAdd(slot, a0); atomicAdd(slot, a1);
        atomicAdd(slot, a2); atomicAdd(slot, a3);
    }
}

__global__ __launch_bounds__(256) void k_loss(const float* __restrict__ loss_part,
                                              float* __restrict__ out) {
    int t = threadIdx.x;
    float a = loss_part[t] + loss_part[t + 256] + loss_part[t + 512] + loss_part[t + 768];
#pragma unroll
    for (int m = 1; m <= 32; m <<= 1) a += __shfl_xor(a, m);
    __shared__ float w[4];
    if ((t & 63) == 0) w[t >> 6] = a;
    __syncthreads();
    if (t == 0) {
        float s = w[0] + w[1] + w[2] + w[3];
        out[ZQ_N] = s * (1.25f / (128.f * 320000.f));
    }
}

extern "C" void kernel_launch(void* const* d_in, const int* in_sizes, int n_in,
                              void* d_out, int out_size, void* d_ws, size_t ws_size,
                              hipStream_t stream) {
    (void)in_sizes; (void)n_in; (void)out_size; (void)ws_size;
    const float* z   = (const float*)d_in[0];
    const float* emb = (const float*)d_in[1];
    const float* An  = (const float*)d_in[2];
    const float* gw  = (const float*)d_in[3];
    const float* gb  = (const float*)d_in[4];
    const float* lsc = (const float*)d_in[5];
    const float* lbi = (const float*)d_in[6];

    float* out     = (float*)d_out;
    float* zq      = out;
    float* idx_out = out + IDX_OFF;

    float* ws        = (float*)d_ws;
    float* refined   = ws + 10240000;        // 10,240,000 (slot 0 unused)
    _Float16* gh_f16 = (_Float16*)(ws + 20480000);  // 16,384 halves (8,192 f)
    _Float16* gl_f16 = (_Float16*)(ws + 20488192);  // 16,384 halves
    _Float16* wh_f16 = (_Float16*)(ws + 20496384);  // 524,288 halves (262,144 f)
    _Float16* wl_f16 = (_Float16*)(ws + 20758528);  // 524,288 halves
    float* s_g       = ws + 21020672;        // 80,000
    float* wsq       = ws + 21100672;        // 4,096
    float* loss_part = ws + 21104768;        // 1,024  (end: 21,105,792 floats)

    k_wsq<<<64, 256, 0, stream>>>(emb, wsq, loss_part);
    k_wsplit<<<256, 256, 0, stream>>>(emb, wh_f16, wl_f16, gw, gh_f16, gl_f16);
    for (int k = 0; k < 4; k++) {
        k_refine<<<3200, 256, 0, stream>>>(z, emb, idx_out, k,
                                           refined, s_g, An,
                                           gh_f16, gl_f16, gb, lsc, lbi);
        k_vq<<<1250, 256, 0, stream>>>(refined,
                                       wh_f16 + k * 131072, wl_f16 + k * 131072,
                                       wsq + k * 1024,
                                       s_g, idx_out, k);
    }
    k_final<<<1250, 256, 0, stream>>>(z, emb, idx_out, zq, loss_part);
    k_loss<<<1, 256, 0, stream>>>(loss_part, out);
}